// Round 1
// baseline (102.783 us; speedup 1.0000x reference)
//
#include <hip/hip_runtime.h>

// UpFilter2d: strided 2x zero-upsample + depthwise 5x5 conv (pad=2), fused.
// x: (B=8, C=128, H=128, W=128) f32, kernel: (C,1,5,5) f32 (identical per
// channel), out: (B, C, 256, 256) f32.
//
// Parity decomposition: out(2ty+py, 2tx+px) only sees kernel taps with
// matching parity. Each thread computes a 2x4 output patch (2 output rows x
// 4 output cols = input cols tx0, tx0+1) from a 3x4 input neighborhood, and
// writes two float4 stores.

#define BB 8
#define CC 128
#define HH 128
#define WW 128

__global__ __launch_bounds__(256) void upfilter2d_kernel(
    const float* __restrict__ x,
    const float* __restrict__ k2d,   // first 25 floats = the 5x5 kernel
    float* __restrict__ out)
{
    const int WH = WW / 2;  // 64 thread-columns per row (each covers 2 input cols)
    int tid  = blockIdx.x * blockDim.x + threadIdx.x;
    int txh  = tid & (WH - 1);        // 0..63
    int rest = tid >> 6;
    int ty   = rest & (HH - 1);       // 0..127
    int bc   = rest >> 7;             // 0..1023  (B*C)

    // 5x5 weights — uniform address, compiler scalarizes to SMEM loads.
    float k[5][5];
#pragma unroll
    for (int i = 0; i < 5; ++i)
#pragma unroll
        for (int j = 0; j < 5; ++j)
            k[i][j] = k2d[i * 5 + j];

    const float* xp = x + (size_t)bc * (HH * WW);
    int tx0 = txh * 2;

    // 3 rows (ty-1, ty, ty+1) x 4 cols (tx0-1 .. tx0+2), zero-padded.
    float v[3][4];
#pragma unroll
    for (int r = 0; r < 3; ++r) {
        int iy = ty - 1 + r;
        bool rowok = (iy >= 0) && (iy < HH);
        const float* rp = xp + iy * WW;
#pragma unroll
        for (int c = 0; c < 4; ++c) {
            int ix = tx0 - 1 + c;
            bool ok = rowok && (ix >= 0) && (ix < WW);
            v[r][c] = ok ? rp[ix] : 0.0f;
        }
    }

    // Even output row (oy = 2ty): kernel rows 0,2,4 over v[0..2].
    // Odd  output row (oy = 2ty+1): kernel rows 1,3 over v[1..2].
    float4 oE = {0.f, 0.f, 0.f, 0.f};
    float4 oO = {0.f, 0.f, 0.f, 0.f};

#pragma unroll
    for (int r = 0; r < 3; ++r) {
        const float* ke = k[2 * r];          // rows 0,2,4
        // even col at base c: cols c,c+1,c+2 with dx=0,2,4
        // odd  col at base c: cols c,c+1   with dx=1,3
        oE.x += ke[0] * v[r][0] + ke[2] * v[r][1] + ke[4] * v[r][2];
        oE.y += ke[1] * v[r][1] + ke[3] * v[r][2];
        oE.z += ke[0] * v[r][1] + ke[2] * v[r][2] + ke[4] * v[r][3];
        oE.w += ke[1] * v[r][2] + ke[3] * v[r][3];
    }
#pragma unroll
    for (int r = 1; r < 3; ++r) {
        const float* ko = k[2 * r - 1];      // rows 1,3
        oO.x += ko[0] * v[r][0] + ko[2] * v[r][1] + ko[4] * v[r][2];
        oO.y += ko[1] * v[r][1] + ko[3] * v[r][2];
        oO.z += ko[0] * v[r][1] + ko[2] * v[r][2] + ko[4] * v[r][3];
        oO.w += ko[1] * v[r][2] + ko[3] * v[r][3];
    }

    const int OW = 2 * WW;  // 256
    size_t obase = (size_t)bc * (2 * HH * OW) + (size_t)(2 * ty) * OW + 4 * txh;
    *reinterpret_cast<float4*>(out + obase)      = oE;
    *reinterpret_cast<float4*>(out + obase + OW) = oO;
}

extern "C" void kernel_launch(void* const* d_in, const int* in_sizes, int n_in,
                              void* d_out, int out_size, void* d_ws, size_t ws_size,
                              hipStream_t stream) {
    const float* x   = (const float*)d_in[0];
    const float* k2d = (const float*)d_in[1];  // (C,1,5,5); all channels identical
    float* out = (float*)d_out;

    // total threads: B*C * H * (W/2) = 8*128*128*64 = 8,388,608
    int total = BB * CC * HH * (WW / 2);
    int block = 256;
    int grid  = total / block;  // 32768
    upfilter2d_kernel<<<grid, block, 0, stream>>>(x, k2d, out);
}